// Round 18
// baseline (1701.433 us; speedup 1.0000x reference)
//
#include <hip/hip_runtime.h>

#define IN_FEAT 1024
#define OUT_FEAT 1024
#define NSAMP 8192
#define KBASE 1024
#define KSPL 8192
// fp6 tiled layout: [rowblk(128)][kb(64)][quad(4)][row(128)][24B]
#define GRANB 24                     /* bytes per 32-elem fp6 granule */
#define KBBYTES (4 * 128 * GRANB)    /* 12288 B: one k-block (K=128) for 128 rows */
#define RBSTRIDE (64L * KBBYTES)     /* 786432 B per 128-row block */

typedef __bf16 v8bf __attribute__((ext_vector_type(8)));
typedef float v4f __attribute__((ext_vector_type(4)));
typedef float v16f __attribute__((ext_vector_type(16)));
typedef float v32f __attribute__((ext_vector_type(32)));
typedef int v8i __attribute__((ext_vector_type(8)));
typedef int v6i __attribute__((ext_vector_type(6)));
typedef unsigned long long u64;

__device__ __forceinline__ void load16_lds(const void* g, void* l) {
  __builtin_amdgcn_global_load_lds(
      (const __attribute__((address_space(1))) void*)g,
      (__attribute__((address_space(3))) void*)l, 16, 0, 0);
}

// fp6 e2m3 encode (round-nearest): e=0/1 step .125 to 1.875; e=2 step .25; e=3 step .5
__device__ __forceinline__ unsigned enc_e2m3(float v) {
  unsigned s = 0u;
  float a = v;
  if (a < 0.f) { s = 32u; a = -a; }
  unsigned code;
  if (a < 1.9375f)      code = (unsigned)rintf(a * 8.0f);
  else if (a < 3.875f)  code = 16u + (unsigned)rintf((a - 2.0f) * 4.0f);
  else if (a < 7.25f)   code = 24u + (unsigned)rintf((a - 4.0f) * 2.0f);
  else                  code = 31u;
  return s | code;
}

// Pack 32 fp32 -> 32 fp6 e2m3 (24 B), HW pk32 convert if available.
__device__ __forceinline__ void pack32_fp6(const float* vals, unsigned char* dst) {
#if __has_builtin(__builtin_amdgcn_cvt_scalef32_pk32_fp6_f32)
  v32f v;
#pragma unroll
  for (int e = 0; e < 32; ++e) v[e] = vals[e];
  v6i r = __builtin_amdgcn_cvt_scalef32_pk32_fp6_f32(v, 1.0f);
  u64* dq = reinterpret_cast<u64*>(dst);
  dq[0] = (u64)(unsigned)r[0] | ((u64)(unsigned)r[1] << 32);
  dq[1] = (u64)(unsigned)r[2] | ((u64)(unsigned)r[3] << 32);
  dq[2] = (u64)(unsigned)r[4] | ((u64)(unsigned)r[5] << 32);
#else
  u64 w0 = 0, w1 = 0, w2 = 0;
#pragma unroll
  for (int e = 0; e < 32; ++e) {
    u64 c = enc_e2m3(vals[e]);
    int bp = 6 * e;
    if (bp < 64) {
      w0 |= c << bp;
      if (bp > 58) w1 |= c >> (64 - bp);
    } else if (bp < 128) {
      w1 |= c << (bp - 64);
      if (bp > 122) w2 |= c >> (128 - bp);
    } else {
      w2 |= c << (bp - 128);
    }
  }
  u64* dq = reinterpret_cast<u64*>(dst);
  dq[0] = w0; dq[1] = w1; dq[2] = w2;
#endif
}

// Granule builder (unchanged).
__global__ __launch_bounds__(256) void build_AB(const float* __restrict__ x,
                                                const float* __restrict__ grid,
                                                const float* __restrict__ bw,
                                                const float* __restrict__ sw,
                                                const float* __restrict__ sc,
                                                __bf16* __restrict__ A1,
                                                unsigned char* __restrict__ A2,
                                                __bf16* __restrict__ B1,
                                                unsigned char* __restrict__ B2) {
  if (blockIdx.x < 8192) {
    __shared__ unsigned lut[256];
    {
      float u = ((float)threadIdx.x + 0.5f) * (1.0f / 256.0f);
      float u2 = u * u, u3 = u2 * u;
      float om = 1.0f - u;
      const float s = 4.0f / 6.0f;
      unsigned c0 = enc_e2m3(om * om * om * s);
      unsigned c1 = enc_e2m3((3.f * u3 - 6.f * u2 + 4.f) * s);
      unsigned c2 = enc_e2m3((-3.f * u3 + 3.f * u2 + 3.f * u + 1.f) * s);
      unsigned c3 = enc_e2m3(u3 * s);
      lut[threadIdx.x] = c0 | (c1 << 6) | (c2 << 12) | (c3 << 18);
    }
    __syncthreads();

    int g = blockIdx.x * 256 + threadIdx.x;
    int r = g & 127;
    int quad = (g >> 7) & 3;
    int kb = (g >> 9) & 63;
    int rb = g >> 15;
    long n = rb * 128 + r;
    int i0 = kb * 16 + quad * 4;

    float4 xv4 = *reinterpret_cast<const float4*>(x + n * IN_FEAT + i0);
    float xs[4] = {xv4.x, xv4.y, xv4.z, xv4.w};

    union { __bf16 h[4]; u64 u; } a1;
#pragma unroll
    for (int j = 0; j < 4; ++j)
      a1.h[j] = (__bf16)(xs[j] / (1.0f + __expf(-xs[j])));
    *reinterpret_cast<u64*>(A1 + n * IN_FEAT + i0) = a1.u;

    u64 w0 = 0, w1 = 0, w2 = 0;
#pragma unroll
    for (int j = 0; j < 4; ++j) {
      float p = (xs[j] + 2.2f) * 2.5f;
      float fl = floorf(p);
      int t0 = (int)fl;
      int idx = (int)((p - fl) * 256.0f) & 255;
      u64 codes = (u64)lut[idx];
      int sh = 6 * t0 - 18; // place c0 at slot t0-3
      u64 seg = (sh >= 0) ? (codes << sh) : (codes >> (-sh));
      seg = ((unsigned)t0 <= 10u) ? (seg & 0xFFFFFFFFFFFFULL) : 0ULL;
      if (j == 0) w0 |= seg;
      else if (j == 1) { w0 |= seg << 48; w1 |= seg >> 16; }
      else if (j == 2) { w1 |= seg << 32; w2 |= seg >> 32; }
      else             { w2 |= seg << 16; }
    }
    u64* dq = reinterpret_cast<u64*>(
        A2 + rb * RBSTRIDE + kb * KBBYTES + quad * (128 * GRANB) + r * GRANB);
    dq[0] = w0; dq[1] = w1; dq[2] = w2;
  } else {
    int g = (blockIdx.x - 8192) * 256 + threadIdx.x;
    int r = g & 127;
    int quad = (g >> 7) & 3;
    int kb = (g >> 9) & 63;
    int ob = g >> 15;
    long o = ob * 128 + r;
    int i0 = kb * 16 + quad * 4;

    float4 bw4 = *reinterpret_cast<const float4*>(bw + o * IN_FEAT + i0);
    union { __bf16 h[4]; u64 u; } b1;
    b1.h[0] = (__bf16)bw4.x; b1.h[1] = (__bf16)bw4.y;
    b1.h[2] = (__bf16)bw4.z; b1.h[3] = (__bf16)bw4.w;
    *reinterpret_cast<u64*>(B1 + o * IN_FEAT + i0) = b1.u;

    float vals[32];
    float4 sc4 = *reinterpret_cast<const float4*>(sc + o * IN_FEAT + i0);
    float scs[4] = {sc4.x, sc4.y, sc4.z, sc4.w};
#pragma unroll
    for (int j = 0; j < 4; ++j) {
      float scale = scs[j] * 256.0f; // 2^8, undone by scaleB=119
      const float4* sp =
          reinterpret_cast<const float4*>(sw + (o * IN_FEAT + i0 + j) * 8);
      float4 p0 = sp[0];
      float4 p1 = sp[1];
      vals[j * 8 + 0] = p0.x * scale; vals[j * 8 + 1] = p0.y * scale;
      vals[j * 8 + 2] = p0.z * scale; vals[j * 8 + 3] = p0.w * scale;
      vals[j * 8 + 4] = p1.x * scale; vals[j * 8 + 5] = p1.y * scale;
      vals[j * 8 + 6] = p1.z * scale; vals[j * 8 + 7] = p1.w * scale;
    }
    pack32_fp6(vals, B2 + (long)ob * RBSTRIDE + kb * KBBYTES +
                         quad * (128 * GRANB) + r * GRANB);
  }
}

// Pipelined fused GEMM v8b — 16 waves/CU at v6's byte count via K-split
// wave pairs. FIX vs v8 (refcheck fail, absmax 3.125): v8 dropped the ni
// accumulator dimension — wave tile declared 64x64 but only 32 cols
// computed (cols [32,64)+[96,128) of every tile left zero). v8b restores
// acc[2][2]: each wave does 4 fp6 MFMAs (its K64 half x 2mi x 2ni) + 2 bf16
// (mi=ws x 2ni). Per pair per iter: fp6 = 8 K64-MFMAs = full K128 x 64x64;
// bf16 each (mi,ni) exactly once. Output coverage: 8 pairs x 64x64 = 256x128. ✓
//  - 1024 threads = 16 waves, 1 block/CU (96 KiB LDS), 256 blocks swizzled.
//  - Staging 48KB/iter, dbuf 2x48KB, counted vmcnt(3), LGKM0+barrier.
//  - Pair reduction via LDS: 2 mi-rounds, ws=1 stores 2x v16f (128B/lane,
//    max offset 65536 <= 98304), ws=0 sums and writes C.
//  LDS per buffer (49152 B): A2 [strip(2)][quad(4)][row(128)][24] @0
//    | B2 [quad(4)][row(128)][24] @24576 | A1 [row(256)][kh(2)][16] @36864
//    | B1 [row(128)][kh(2)][16] @45056.
__global__ __launch_bounds__(1024, 4) void gemm_fused(const unsigned char* __restrict__ A2,
                                                      const unsigned char* __restrict__ B2,
                                                      const __bf16* __restrict__ A1,
                                                      const __bf16* __restrict__ B1,
                                                      float* __restrict__ C) {
  __shared__ __attribute__((aligned(16))) unsigned char smem[98304];

  const int tid = threadIdx.x;
  // XCD swizzle: flat 0..255 (256 % 8 == 0, bijective).
  const int flat = blockIdx.x;
  const int swz = (flat & 7) * 32 + (flat >> 3);
  const int bm = swz >> 3;  // 0..31
  const int bn = swz & 7;   // 0..7

  const int lane = tid & 63;
  const int w = tid >> 6;        // 0..15
  const int ws = w >> 3;         // 0/1: k-split half
  const int p = w & 7;           // pair id
  const int wm = (p >> 1) * 64;  // 4 row-quarters of 256
  const int wn = (p & 1) * 64;   // 2 col-halves of 128
  const int l32 = lane & 31;
  const int hi = lane >> 5;      // 0/1 -> k-chunk within the wave's half

  // Staging: 3 x 16B per thread per iter, flat dest f = tid*16 + j*16384.
  const unsigned char* sp[3];
  int stp[3];
#pragma unroll
  for (int j = 0; j < 3; ++j) {
    const int f = tid * 16 + j * 16384;
    if (f < 12288) {
      sp[j] = A2 + (long)(2 * bm) * RBSTRIDE + f;              stp[j] = KBBYTES;
    } else if (f < 24576) {
      sp[j] = A2 + (long)(2 * bm + 1) * RBSTRIDE + (f - 12288); stp[j] = KBBYTES;
    } else if (f < 36864) {
      sp[j] = B2 + (long)bn * RBSTRIDE + (f - 24576);          stp[j] = KBBYTES;
    } else if (f < 45056) {
      int off = f - 36864, row = off >> 5, kh = (off >> 4) & 1;
      sp[j] = (const unsigned char*)A1 + (long)(bm * 256 + row) * 2048 + kh * 16;
      stp[j] = 32;
    } else {
      int off = f - 45056, row = off >> 5, kh = (off >> 4) & 1;
      sp[j] = (const unsigned char*)B1 + (long)(bn * 128 + row) * 2048 + kh * 16;
      stp[j] = 32;
    }
  }

  // fp6 frag offsets (buffer-relative); quad = ws*2 + hi.
  const int q = ws * 2 + hi;
  int aOff[2], bOff[2];
#pragma unroll
  for (int mi = 0; mi < 2; ++mi) {
    const int row = wm + mi * 32 + l32;
    aOff[mi] = (row >> 7) * 12288 + q * 3072 + (row & 127) * GRANB;
  }
#pragma unroll
  for (int ni = 0; ni < 2; ++ni)
    bOff[ni] = 24576 + q * 3072 + (wn + ni * 32 + l32) * GRANB;
  // bf16 frag offsets: this wave computes bf16 for mi = ws only, both ni.
  const int aHOff = 36864 + (wm + ws * 32 + l32) * 32 + hi * 16;
  int bHOff[2];
#pragma unroll
  for (int ni = 0; ni < 2; ++ni)
    bHOff[ni] = 45056 + (wn + ni * 32 + l32) * 32 + hi * 16;

  v16f acc[2][2] = {};  // partials over this wave's k-half: acc[mi][ni]

  auto stage = [&](int it) {
    unsigned char* db = smem + (size_t)(it & 1) * 49152;
#pragma unroll
    for (int j = 0; j < 3; ++j)
      load16_lds(sp[j] + (long)(it * stp[j]), db + tid * 16 + j * 16384);
  };

  auto compute = [&](int it) {
    const unsigned char* db = smem + (size_t)(it & 1) * 49152;
    // fp6: this wave's K64 half (quads ws*2+hi), all mi x ni.
    v8i af[2], bf[2];
#pragma unroll
    for (int mi = 0; mi < 2; ++mi) {
      const unsigned char* rb = db + aOff[mi];
      u64 a0 = *reinterpret_cast<const u64*>(rb);
      u64 a1v = *reinterpret_cast<const u64*>(rb + 8);
      u64 a2v = *reinterpret_cast<const u64*>(rb + 16);
      v8i f = {(int)a0, (int)(a0 >> 32), (int)a1v, (int)(a1v >> 32),
               (int)a2v, (int)(a2v >> 32), 0, 0};
      af[mi] = f;
    }
#pragma unroll
    for (int ni = 0; ni < 2; ++ni) {
      const unsigned char* rb = db + bOff[ni];
      u64 b0 = *reinterpret_cast<const u64*>(rb);
      u64 b1v = *reinterpret_cast<const u64*>(rb + 8);
      u64 b2v = *reinterpret_cast<const u64*>(rb + 16);
      v8i f = {(int)b0, (int)(b0 >> 32), (int)b1v, (int)(b1v >> 32),
               (int)b2v, (int)(b2v >> 32), 0, 0};
      bf[ni] = f;
    }
    // bf16 frags for mi = ws (k = it*16 + hi*8 + e), both ni.
    v8bf a1f = *reinterpret_cast<const v8bf*>(db + aHOff);
    v8bf b1f[2];
#pragma unroll
    for (int ni = 0; ni < 2; ++ni)
      b1f[ni] = *reinterpret_cast<const v8bf*>(db + bHOff[ni]);
#pragma unroll
    for (int mi = 0; mi < 2; ++mi)
#pragma unroll
      for (int ni = 0; ni < 2; ++ni)
        // fmt 2 = fp6 e2m3 both; scaleA=125 (2^-2), scaleB=119 (2^-8)
        acc[mi][ni] = __builtin_amdgcn_mfma_scale_f32_32x32x64_f8f6f4(
            af[mi], bf[ni], acc[mi][ni], 2, 2, 0, 125, 0, 119);
#pragma unroll
    for (int ni = 0; ni < 2; ++ni)
      acc[ws][ni] = __builtin_amdgcn_mfma_f32_32x32x16_bf16(
          a1f, b1f[ni], acc[ws][ni], 0, 0, 0);
  };

#define VM_WAIT3() asm volatile("s_waitcnt vmcnt(3)" ::: "memory")
#define VM_WAIT0() asm volatile("s_waitcnt vmcnt(0)" ::: "memory")
#define LGKM0()    asm volatile("s_waitcnt lgkmcnt(0)" ::: "memory")
#define BARRIER()  asm volatile("s_barrier" ::: "memory")

  stage(0);
#pragma unroll 1
  for (int it = 0; it < 63; ++it) {
    stage(it + 1);
    VM_WAIT3();   // waits only tile-it's 3 loads; it+1's stay in flight
    BARRIER();
    compute(it);
    LGKM0();      // all ds_reads retired before next stage overwrites buffer
    BARRIER();
  }
  VM_WAIT0();
  BARRIER();
  compute(63);
  LGKM0();
  BARRIER();      // epilogue LDS stores overlap buffer regions: drain first

  // Pair reduction + C write. Two mi-rounds; ws=1 stores both ni partials
  // (128B/lane, pair stride 8192, max 65536 <= 98304), ws=0 adds + writes.
  // 32x32 C/D layout (m74/m101): col=lane&31, row=(r&3)+8*(r>>2)+4*(lane>>5).
#pragma unroll 1
  for (int mi = 0; mi < 2; ++mi) {
    if (ws == 1) {
      *reinterpret_cast<v16f*>(smem + p * 8192 + lane * 128) = acc[mi][0];
      *reinterpret_cast<v16f*>(smem + p * 8192 + lane * 128 + 64) = acc[mi][1];
    }
    BARRIER();
    if (ws == 0) {
#pragma unroll
      for (int ni = 0; ni < 2; ++ni) {
        v16f other = *reinterpret_cast<const v16f*>(
            smem + p * 8192 + lane * 128 + ni * 64);
        v16f sum = acc[mi][ni] + other;
#pragma unroll
        for (int r = 0; r < 16; ++r) {
          int row = bm * 256 + wm + mi * 32 + (r & 3) + 8 * (r >> 2) + 4 * hi;
          int col = bn * 128 + wn + ni * 32 + l32;
          C[(long)row * OUT_FEAT + col] = sum[r];
        }
      }
    }
    BARRIER();
  }
}

extern "C" void kernel_launch(void* const* d_in, const int* in_sizes, int n_in,
                              void* d_out, int out_size, void* d_ws, size_t ws_size,
                              hipStream_t stream) {
  const float* x = (const float*)d_in[0];
  const float* bw = (const float*)d_in[1];
  const float* sw = (const float*)d_in[2];
  const float* sc = (const float*)d_in[3];
  const float* grid = (const float*)d_in[4];
  float* out = (float*)d_out;

  // ws: A1 bf16 16.8MB | A2 fp6 50.3MB | B1 bf16 2MB | B2 fp6 6.3MB
  __bf16* A1 = (__bf16*)d_ws;
  unsigned char* A2 = (unsigned char*)(A1 + (size_t)NSAMP * KBASE);
  __bf16* B1 = (__bf16*)(A2 + 64L * RBSTRIDE);
  unsigned char* B2 = (unsigned char*)(B1 + (size_t)OUT_FEAT * KBASE);

  build_AB<<<8192 + 1024, 256, 0, stream>>>(x, grid, bw, sw, sc, A1, A2, B1, B2);
  gemm_fused<<<256, 1024, 0, stream>>>(A2, B2, A1, B1, out);
}

// Round 20
// 237.585 us; speedup vs baseline: 7.1614x; 7.1614x over previous
//
#include <hip/hip_runtime.h>

#define IN_FEAT 1024
#define OUT_FEAT 1024
#define NSAMP 8192
#define KBASE 1024
#define KSPL 8192
// fp6 tiled layout: [rowblk(128)][kb(64)][quad(4)][row(128)][24B]
#define GRANB 24                     /* bytes per 32-elem fp6 granule */
#define KBBYTES (4 * 128 * GRANB)    /* 12288 B: one k-block (K=128) for 128 rows */
#define RBSTRIDE (64L * KBBYTES)     /* 786432 B per 128-row block */

typedef __bf16 v8bf __attribute__((ext_vector_type(8)));
typedef float v4f __attribute__((ext_vector_type(4)));
typedef float v16f __attribute__((ext_vector_type(16)));
typedef float v32f __attribute__((ext_vector_type(32)));
typedef int v8i __attribute__((ext_vector_type(8)));
typedef int v6i __attribute__((ext_vector_type(6)));
typedef unsigned long long u64;

__device__ __forceinline__ void load16_lds(const void* g, void* l) {
  __builtin_amdgcn_global_load_lds(
      (const __attribute__((address_space(1))) void*)g,
      (__attribute__((address_space(3))) void*)l, 16, 0, 0);
}

// fp6 e2m3 encode (round-nearest): e=0/1 step .125 to 1.875; e=2 step .25; e=3 step .5
__device__ __forceinline__ unsigned enc_e2m3(float v) {
  unsigned s = 0u;
  float a = v;
  if (a < 0.f) { s = 32u; a = -a; }
  unsigned code;
  if (a < 1.9375f)      code = (unsigned)rintf(a * 8.0f);
  else if (a < 3.875f)  code = 16u + (unsigned)rintf((a - 2.0f) * 4.0f);
  else if (a < 7.25f)   code = 24u + (unsigned)rintf((a - 4.0f) * 2.0f);
  else                  code = 31u;
  return s | code;
}

// Pack 32 fp32 -> 32 fp6 e2m3 (24 B), HW pk32 convert if available.
__device__ __forceinline__ void pack32_fp6(const float* vals, unsigned char* dst) {
#if __has_builtin(__builtin_amdgcn_cvt_scalef32_pk32_fp6_f32)
  v32f v;
#pragma unroll
  for (int e = 0; e < 32; ++e) v[e] = vals[e];
  v6i r = __builtin_amdgcn_cvt_scalef32_pk32_fp6_f32(v, 1.0f);
  u64* dq = reinterpret_cast<u64*>(dst);
  dq[0] = (u64)(unsigned)r[0] | ((u64)(unsigned)r[1] << 32);
  dq[1] = (u64)(unsigned)r[2] | ((u64)(unsigned)r[3] << 32);
  dq[2] = (u64)(unsigned)r[4] | ((u64)(unsigned)r[5] << 32);
#else
  u64 w0 = 0, w1 = 0, w2 = 0;
#pragma unroll
  for (int e = 0; e < 32; ++e) {
    u64 c = enc_e2m3(vals[e]);
    int bp = 6 * e;
    if (bp < 64) {
      w0 |= c << bp;
      if (bp > 58) w1 |= c >> (64 - bp);
    } else if (bp < 128) {
      w1 |= c << (bp - 64);
      if (bp > 122) w2 |= c >> (128 - bp);
    } else {
      w2 |= c << (bp - 128);
    }
  }
  u64* dq = reinterpret_cast<u64*>(dst);
  dq[0] = w0; dq[1] = w1; dq[2] = w2;
#endif
}

// Granule builder (unchanged).
__global__ __launch_bounds__(256) void build_AB(const float* __restrict__ x,
                                                const float* __restrict__ grid,
                                                const float* __restrict__ bw,
                                                const float* __restrict__ sw,
                                                const float* __restrict__ sc,
                                                __bf16* __restrict__ A1,
                                                unsigned char* __restrict__ A2,
                                                __bf16* __restrict__ B1,
                                                unsigned char* __restrict__ B2) {
  if (blockIdx.x < 8192) {
    __shared__ unsigned lut[256];
    {
      float u = ((float)threadIdx.x + 0.5f) * (1.0f / 256.0f);
      float u2 = u * u, u3 = u2 * u;
      float om = 1.0f - u;
      const float s = 4.0f / 6.0f;
      unsigned c0 = enc_e2m3(om * om * om * s);
      unsigned c1 = enc_e2m3((3.f * u3 - 6.f * u2 + 4.f) * s);
      unsigned c2 = enc_e2m3((-3.f * u3 + 3.f * u2 + 3.f * u + 1.f) * s);
      unsigned c3 = enc_e2m3(u3 * s);
      lut[threadIdx.x] = c0 | (c1 << 6) | (c2 << 12) | (c3 << 18);
    }
    __syncthreads();

    int g = blockIdx.x * 256 + threadIdx.x;
    int r = g & 127;
    int quad = (g >> 7) & 3;
    int kb = (g >> 9) & 63;
    int rb = g >> 15;
    long n = rb * 128 + r;
    int i0 = kb * 16 + quad * 4;

    float4 xv4 = *reinterpret_cast<const float4*>(x + n * IN_FEAT + i0);
    float xs[4] = {xv4.x, xv4.y, xv4.z, xv4.w};

    union { __bf16 h[4]; u64 u; } a1;
#pragma unroll
    for (int j = 0; j < 4; ++j)
      a1.h[j] = (__bf16)(xs[j] / (1.0f + __expf(-xs[j])));
    *reinterpret_cast<u64*>(A1 + n * IN_FEAT + i0) = a1.u;

    u64 w0 = 0, w1 = 0, w2 = 0;
#pragma unroll
    for (int j = 0; j < 4; ++j) {
      float p = (xs[j] + 2.2f) * 2.5f;
      float fl = floorf(p);
      int t0 = (int)fl;
      int idx = (int)((p - fl) * 256.0f) & 255;
      u64 codes = (u64)lut[idx];
      int sh = 6 * t0 - 18; // place c0 at slot t0-3
      u64 seg = (sh >= 0) ? (codes << sh) : (codes >> (-sh));
      seg = ((unsigned)t0 <= 10u) ? (seg & 0xFFFFFFFFFFFFULL) : 0ULL;
      if (j == 0) w0 |= seg;
      else if (j == 1) { w0 |= seg << 48; w1 |= seg >> 16; }
      else if (j == 2) { w1 |= seg << 32; w2 |= seg >> 32; }
      else             { w2 |= seg << 16; }
    }
    u64* dq = reinterpret_cast<u64*>(
        A2 + rb * RBSTRIDE + kb * KBBYTES + quad * (128 * GRANB) + r * GRANB);
    dq[0] = w0; dq[1] = w1; dq[2] = w2;
  } else {
    int g = (blockIdx.x - 8192) * 256 + threadIdx.x;
    int r = g & 127;
    int quad = (g >> 7) & 3;
    int kb = (g >> 9) & 63;
    int ob = g >> 15;
    long o = ob * 128 + r;
    int i0 = kb * 16 + quad * 4;

    float4 bw4 = *reinterpret_cast<const float4*>(bw + o * IN_FEAT + i0);
    union { __bf16 h[4]; u64 u; } b1;
    b1.h[0] = (__bf16)bw4.x; b1.h[1] = (__bf16)bw4.y;
    b1.h[2] = (__bf16)bw4.z; b1.h[3] = (__bf16)bw4.w;
    *reinterpret_cast<u64*>(B1 + o * IN_FEAT + i0) = b1.u;

    float vals[32];
    float4 sc4 = *reinterpret_cast<const float4*>(sc + o * IN_FEAT + i0);
    float scs[4] = {sc4.x, sc4.y, sc4.z, sc4.w};
#pragma unroll
    for (int j = 0; j < 4; ++j) {
      float scale = scs[j] * 256.0f; // 2^8, undone by scaleB=119
      const float4* sp =
          reinterpret_cast<const float4*>(sw + (o * IN_FEAT + i0 + j) * 8);
      float4 p0 = sp[0];
      float4 p1 = sp[1];
      vals[j * 8 + 0] = p0.x * scale; vals[j * 8 + 1] = p0.y * scale;
      vals[j * 8 + 2] = p0.z * scale; vals[j * 8 + 3] = p0.w * scale;
      vals[j * 8 + 4] = p1.x * scale; vals[j * 8 + 5] = p1.y * scale;
      vals[j * 8 + 6] = p1.z * scale; vals[j * 8 + 7] = p1.w * scale;
    }
    pack32_fp6(vals, B2 + (long)ob * RBSTRIDE + kb * KBBYTES +
                         quad * (128 * GRANB) + r * GRANB);
  }
}

// Pipelined fused GEMM v8c — 16 waves/CU at v6's byte count via K-split
// wave pairs. FIX vs v8b (1689us, WRITE_SIZE 5GB, VGPR 60): rule #20 —
// `acc[ws][ni]` with RUNTIME ws (and the `#pragma unroll 1` mi epilogue)
// demoted the whole accumulator array to scratch; every MFMA round-tripped
// 64B through HBM. v8c: ws is wave-uniform -> static-index branch for the
// bf16 MFMAs; epilogue mi-loop fully unrolled (barriers remain uniform).
//  Structure (unchanged from v8b, refcheck'd): 1024 thr = 16 waves,
//  1 block/CU, 256 blocks swizzled; wave PAIR (ws=0/1) per 64x64 tile
//  splits K128: fp6 quads {2ws, 2ws+1} x 2mi x 2ni; bf16 mi=ws x 2ni.
//  Staging 48KB/iter, dbuf 2x48KB, counted vmcnt(3), LGKM0+barrier;
//  pair reduction via LDS (2 mi-rounds).
//  LDS per buffer (49152 B): A2 [strip(2)][quad(4)][row(128)][24] @0
//    | B2 [quad(4)][row(128)][24] @24576 | A1 [row(256)][kh(2)][16] @36864
//    | B1 [row(128)][kh(2)][16] @45056.
__global__ __launch_bounds__(1024, 4) void gemm_fused(const unsigned char* __restrict__ A2,
                                                      const unsigned char* __restrict__ B2,
                                                      const __bf16* __restrict__ A1,
                                                      const __bf16* __restrict__ B1,
                                                      float* __restrict__ C) {
  __shared__ __attribute__((aligned(16))) unsigned char smem[98304];

  const int tid = threadIdx.x;
  // XCD swizzle: flat 0..255 (256 % 8 == 0, bijective).
  const int flat = blockIdx.x;
  const int swz = (flat & 7) * 32 + (flat >> 3);
  const int bm = swz >> 3;  // 0..31
  const int bn = swz & 7;   // 0..7

  const int lane = tid & 63;
  const int w = tid >> 6;        // 0..15
  const int ws = w >> 3;         // 0/1: k-split half (wave-uniform)
  const int p = w & 7;           // pair id
  const int wm = (p >> 1) * 64;  // 4 row-quarters of 256
  const int wn = (p & 1) * 64;   // 2 col-halves of 128
  const int l32 = lane & 31;
  const int hi = lane >> 5;      // 0/1 -> k-chunk within the wave's half

  // Staging: 3 x 16B per thread per iter, flat dest f = tid*16 + j*16384.
  const unsigned char* sp[3];
  int stp[3];
#pragma unroll
  for (int j = 0; j < 3; ++j) {
    const int f = tid * 16 + j * 16384;
    if (f < 12288) {
      sp[j] = A2 + (long)(2 * bm) * RBSTRIDE + f;              stp[j] = KBBYTES;
    } else if (f < 24576) {
      sp[j] = A2 + (long)(2 * bm + 1) * RBSTRIDE + (f - 12288); stp[j] = KBBYTES;
    } else if (f < 36864) {
      sp[j] = B2 + (long)bn * RBSTRIDE + (f - 24576);          stp[j] = KBBYTES;
    } else if (f < 45056) {
      int off = f - 36864, row = off >> 5, kh = (off >> 4) & 1;
      sp[j] = (const unsigned char*)A1 + (long)(bm * 256 + row) * 2048 + kh * 16;
      stp[j] = 32;
    } else {
      int off = f - 45056, row = off >> 5, kh = (off >> 4) & 1;
      sp[j] = (const unsigned char*)B1 + (long)(bn * 128 + row) * 2048 + kh * 16;
      stp[j] = 32;
    }
  }

  // fp6 frag offsets (buffer-relative); quad = ws*2 + hi.
  const int q = ws * 2 + hi;
  int aOff[2], bOff[2];
#pragma unroll
  for (int mi = 0; mi < 2; ++mi) {
    const int row = wm + mi * 32 + l32;
    aOff[mi] = (row >> 7) * 12288 + q * 3072 + (row & 127) * GRANB;
  }
#pragma unroll
  for (int ni = 0; ni < 2; ++ni)
    bOff[ni] = 24576 + q * 3072 + (wn + ni * 32 + l32) * GRANB;
  // bf16 frag offsets: this wave computes bf16 for mi = ws only, both ni.
  const int aHOff = 36864 + (wm + ws * 32 + l32) * 32 + hi * 16;
  int bHOff[2];
#pragma unroll
  for (int ni = 0; ni < 2; ++ni)
    bHOff[ni] = 45056 + (wn + ni * 32 + l32) * 32 + hi * 16;

  v16f acc[2][2] = {};  // partials over this wave's k-half: acc[mi][ni]
                        // ALL indices compile-time (rule #20).

  auto stage = [&](int it) {
    unsigned char* db = smem + (size_t)(it & 1) * 49152;
#pragma unroll
    for (int j = 0; j < 3; ++j)
      load16_lds(sp[j] + (long)(it * stp[j]), db + tid * 16 + j * 16384);
  };

  auto compute = [&](int it) {
    const unsigned char* db = smem + (size_t)(it & 1) * 49152;
    // fp6: this wave's K64 half (quads ws*2+hi), all mi x ni.
    v8i af[2], bf[2];
#pragma unroll
    for (int mi = 0; mi < 2; ++mi) {
      const unsigned char* rb = db + aOff[mi];
      u64 a0 = *reinterpret_cast<const u64*>(rb);
      u64 a1v = *reinterpret_cast<const u64*>(rb + 8);
      u64 a2v = *reinterpret_cast<const u64*>(rb + 16);
      v8i f = {(int)a0, (int)(a0 >> 32), (int)a1v, (int)(a1v >> 32),
               (int)a2v, (int)(a2v >> 32), 0, 0};
      af[mi] = f;
    }
#pragma unroll
    for (int ni = 0; ni < 2; ++ni) {
      const unsigned char* rb = db + bOff[ni];
      u64 b0 = *reinterpret_cast<const u64*>(rb);
      u64 b1v = *reinterpret_cast<const u64*>(rb + 8);
      u64 b2v = *reinterpret_cast<const u64*>(rb + 16);
      v8i f = {(int)b0, (int)(b0 >> 32), (int)b1v, (int)(b1v >> 32),
               (int)b2v, (int)(b2v >> 32), 0, 0};
      bf[ni] = f;
    }
    // bf16 frags for mi = ws (k = it*16 + hi*8 + e), both ni.
    v8bf a1f = *reinterpret_cast<const v8bf*>(db + aHOff);
    v8bf b1f[2];
#pragma unroll
    for (int ni = 0; ni < 2; ++ni)
      b1f[ni] = *reinterpret_cast<const v8bf*>(db + bHOff[ni]);
#pragma unroll
    for (int mi = 0; mi < 2; ++mi)
#pragma unroll
      for (int ni = 0; ni < 2; ++ni)
        // fmt 2 = fp6 e2m3 both; scaleA=125 (2^-2), scaleB=119 (2^-8)
        acc[mi][ni] = __builtin_amdgcn_mfma_scale_f32_32x32x64_f8f6f4(
            af[mi], bf[ni], acc[mi][ni], 2, 2, 0, 125, 0, 119);
    // ws is wave-uniform: static-index branch keeps acc in registers.
    if (ws == 0) {
      acc[0][0] = __builtin_amdgcn_mfma_f32_32x32x16_bf16(a1f, b1f[0], acc[0][0], 0, 0, 0);
      acc[0][1] = __builtin_amdgcn_mfma_f32_32x32x16_bf16(a1f, b1f[1], acc[0][1], 0, 0, 0);
    } else {
      acc[1][0] = __builtin_amdgcn_mfma_f32_32x32x16_bf16(a1f, b1f[0], acc[1][0], 0, 0, 0);
      acc[1][1] = __builtin_amdgcn_mfma_f32_32x32x16_bf16(a1f, b1f[1], acc[1][1], 0, 0, 0);
    }
  };

#define VM_WAIT3() asm volatile("s_waitcnt vmcnt(3)" ::: "memory")
#define VM_WAIT0() asm volatile("s_waitcnt vmcnt(0)" ::: "memory")
#define LGKM0()    asm volatile("s_waitcnt lgkmcnt(0)" ::: "memory")
#define BARRIER()  asm volatile("s_barrier" ::: "memory")

  stage(0);
#pragma unroll 1
  for (int it = 0; it < 63; ++it) {
    stage(it + 1);
    VM_WAIT3();   // waits only tile-it's 3 loads; it+1's stay in flight
    BARRIER();
    compute(it);
    LGKM0();      // all ds_reads retired before next stage overwrites buffer
    BARRIER();
  }
  VM_WAIT0();
  BARRIER();
  compute(63);
  LGKM0();
  BARRIER();      // epilogue LDS stores overlap buffer regions: drain first

  // Pair reduction + C write. FULLY UNROLLED mi (static acc indices);
  // ws=1 stores both ni partials (128B/lane, pair stride 8192, max 65536
  // <= 98304), ws=0 adds + writes. 32x32 C/D layout (m74/m101):
  // col=lane&31, row=(r&3)+8*(r>>2)+4*(lane>>5).
#pragma unroll
  for (int mi = 0; mi < 2; ++mi) {
    if (ws == 1) {
      *reinterpret_cast<v16f*>(smem + p * 8192 + lane * 128) = acc[mi][0];
      *reinterpret_cast<v16f*>(smem + p * 8192 + lane * 128 + 64) = acc[mi][1];
    }
    BARRIER();
    if (ws == 0) {
#pragma unroll
      for (int ni = 0; ni < 2; ++ni) {
        v16f other = *reinterpret_cast<const v16f*>(
            smem + p * 8192 + lane * 128 + ni * 64);
        v16f sum = acc[mi][ni] + other;
#pragma unroll
        for (int r = 0; r < 16; ++r) {
          int row = bm * 256 + wm + mi * 32 + (r & 3) + 8 * (r >> 2) + 4 * hi;
          int col = bn * 128 + wn + ni * 32 + l32;
          C[(long)row * OUT_FEAT + col] = sum[r];
        }
      }
    }
    BARRIER();
  }
}

extern "C" void kernel_launch(void* const* d_in, const int* in_sizes, int n_in,
                              void* d_out, int out_size, void* d_ws, size_t ws_size,
                              hipStream_t stream) {
  const float* x = (const float*)d_in[0];
  const float* bw = (const float*)d_in[1];
  const float* sw = (const float*)d_in[2];
  const float* sc = (const float*)d_in[3];
  const float* grid = (const float*)d_in[4];
  float* out = (float*)d_out;

  // ws: A1 bf16 16.8MB | A2 fp6 50.3MB | B1 bf16 2MB | B2 fp6 6.3MB
  __bf16* A1 = (__bf16*)d_ws;
  unsigned char* A2 = (unsigned char*)(A1 + (size_t)NSAMP * KBASE);
  __bf16* B1 = (__bf16*)(A2 + 64L * RBSTRIDE);
  unsigned char* B2 = (unsigned char*)(B1 + (size_t)OUT_FEAT * KBASE);

  build_AB<<<8192 + 1024, 256, 0, stream>>>(x, grid, bw, sw, sc, A1, A2, B1, B2);
  gemm_fused<<<256, 1024, 0, stream>>>(A2, B2, A1, B1, out);
}